// Round 2
// baseline (104.615 us; speedup 1.0000x reference)
//
#include <hip/hip_runtime.h>
#include <hip/hip_bf16.h>

#define S_LEN 4096
#define DIM   128
#define NB    4
#define BQ    256          // q rows per block (4 waves x 64)
#define BKT   128          // k rows per staged tile / iteration
#define CH    3            // K-tiles per chunk (split-K granularity)
#define NQT   (S_LEN / BQ) // 16 q tiles per batch

typedef __bf16 bf16_t;
typedef __attribute__((ext_vector_type(8)))  __bf16       bf16x8;
typedef __attribute__((ext_vector_type(16))) float        f32x16;
typedef __attribute__((ext_vector_type(4)))  unsigned int u32x4;

#define MFMA32(a, b, c) __builtin_amdgcn_mfma_f32_32x32x16_bf16((a), (b), (c), 0, 0, 0)

// v_cvt_pk_bf16_f32: dst.lo = bf16(a), dst.hi = bf16(b)
#define CVTPK(d, a, b) asm("v_cvt_pk_bf16_f32 %0, %1, %2" : "=v"(d) : "v"(a), "v"(b))
// v_permlane32_swap_b32 vdst, vsrc: vdst HIGH lanes <-> vsrc LOW lanes
// (direction derived from hardware-verified m214 v22 recipe)
#define PSWAP(d, s)    asm("v_permlane32_swap_b32 %0, %1" : "+v"(d), "+v"(s))

// ---------------- preprocessing: RoPE(Q,K) -> bf16 ----------------
__global__ void rope_pack_kernel(const float* __restrict__ Q,
                                 const float* __restrict__ K,
                                 bf16_t* __restrict__ Qr,
                                 bf16_t* __restrict__ Kr) {
    int t   = threadIdx.x;
    int i   = t & 63;                      // freq index 0..63
    int row = blockIdx.x * 4 + (t >> 6);   // global row in [0, B*S)
    int s   = row & (S_LEN - 1);
    size_t base = (size_t)row * DIM;
    // angle = s * 10000^(-i/64); work in revolutions for v_sin/v_cos
    float e       = -(float)i * (13.287712379549449f / 64.0f); // log2(10000)/64
    float inv_rev = exp2f(e) * 0.15915494309189535f;           // /(2*pi)
    float rev = (float)s * inv_rev;
    float fr  = rev - floorf(rev);
    float c  = __builtin_amdgcn_cosf(fr);
    float sn = __builtin_amdgcn_sinf(fr);
    float q1 = Q[base + i], q2 = Q[base + i + 64];
    float k1 = K[base + i], k2 = K[base + i + 64];
    Qr[base + i]      = (bf16_t)(q1 * c - q2 * sn);
    Qr[base + i + 64] = (bf16_t)(q2 * c + q1 * sn);
    Kr[base + i]      = (bf16_t)(k1 * c - k2 * sn);
    Kr[base + i + 64] = (bf16_t)(k2 * c + k1 * sn);
}

// ---------------- preprocessing: V -> V^T bf16 [B][D][S] ----------------
__global__ void vt_pack_kernel(const float* __restrict__ V, bf16_t* __restrict__ Vt) {
    int b  = blockIdx.y;
    int s0 = blockIdx.x * 64;
    int t  = threadIdx.x;
    int d  = t >> 1;
    int sh = (t & 1) * 32;
    const float* vb = V + (size_t)b * S_LEN * DIM;
    bf16_t* ob = Vt + ((size_t)b * DIM + d) * S_LEN;
    #pragma unroll
    for (int j8 = 0; j8 < 4; ++j8) {
        bf16x8 u;
        #pragma unroll
        for (int e2 = 0; e2 < 8; ++e2) {
            int s = s0 + sh + j8 * 8 + e2;
            u[e2] = (bf16_t)vb[(size_t)s * DIM + d];
        }
        *(bf16x8*)(ob + s0 + sh + j8 * 8) = u;   // 16B store, contiguous in s
    }
}

// ---------------- main: O += tril(Qr Kr^T) V ----------------
__device__ __forceinline__ unsigned swzo(int row, int colByte) {
    // 256B rows; XOR-swizzle 16B slots by (row&15) -> conflict-light b128 col reads
    return (unsigned)(row * 256 + (colByte ^ ((row & 15) << 4)));
}

__device__ __forceinline__ void cvt_swap(const f32x16& s, unsigned int w[8]) {
    CVTPK(w[0], s[0],  s[1]);  CVTPK(w[1], s[2],  s[3]);
    CVTPK(w[2], s[4],  s[5]);  CVTPK(w[3], s[6],  s[7]);
    CVTPK(w[4], s[8],  s[9]);  CVTPK(w[5], s[10], s[11]);
    CVTPK(w[6], s[12], s[13]); CVTPK(w[7], s[14], s[15]);
    // dst-high <-> src-low: after swaps {w0..w3} = A-frag k 0..15 (k=8*lg+e),
    // {w4..w7} = k 16..31
    PSWAP(w[0], w[2]); PSWAP(w[1], w[3]);
    PSWAP(w[4], w[6]); PSWAP(w[5], w[7]);
}

__launch_bounds__(256, 2)
__global__ void attn_main_kernel(const bf16_t* __restrict__ Qr,
                                 const bf16_t* __restrict__ Kr,
                                 const bf16_t* __restrict__ Vt,
                                 float* __restrict__ Out) {
    __shared__ bf16_t Kt[128 * 128];  // 32 KB, swizzled [k][d]
    __shared__ bf16_t Vl[128 * 128];  // 32 KB, swizzled [d][k]

    // decode (batch, q-tile, chunk); big tiles first (LPT-ish dispatch)
    int b = blockIdx.x & 3;
    int t = blockIdx.x >> 2;
    int qt = 0, c0 = 0;
    for (int i2 = NQT - 1; i2 >= 0; --i2) {
        int n = (2 * (i2 + 1) + CH - 1) / CH;
        if (t < n) { qt = i2; c0 = t; break; }
        t -= n;
    }
    int nkt   = 2 * (qt + 1);            // K-tiles needed by this q-tile
    int kt_lo = c0 * CH;
    int kt_hi = min(kt_lo + CH, nkt);
    bool single = ((nkt + CH - 1) / CH) == 1;   // only qt=0: plain store

    int tid  = threadIdx.x;
    int w    = tid >> 6;
    int lane = tid & 63;
    int lr   = lane & 31;
    int lg   = lane >> 5;

    int q0 = qt * BQ;
    int qw = q0 + w * 64;                // this wave's 64 q rows

    const bf16_t* Qb = Qr + (size_t)b * S_LEN * DIM;
    const bf16_t* Kb = Kr + (size_t)b * S_LEN * DIM;
    const bf16_t* Vb = Vt + (size_t)b * DIM * S_LEN;

    // Q as MFMA-B fragments, resident in regs: [qblock][d-slice of 16]
    bf16x8 qf[2][8];
    #pragma unroll
    for (int qb = 0; qb < 2; ++qb)
        #pragma unroll
        for (int s2 = 0; s2 < 8; ++s2)
            qf[qb][s2] = *(const bf16x8*)(Qb + (size_t)(qw + qb * 32 + lr) * DIM
                                          + s2 * 16 + lg * 8);

    f32x16 acc[2][4];
    #pragma unroll
    for (int qb = 0; qb < 2; ++qb)
        #pragma unroll
        for (int db = 0; db < 4; ++db)
            #pragma unroll
            for (int r = 0; r < 16; ++r) acc[qb][db][r] = 0.f;

    for (int kt = kt_lo; kt < kt_hi; ++kt) {
        int kbase = kt * BKT;
        // stage K(RoPE'd) and V^T tiles (128x128 bf16 each), swizzled
        #pragma unroll
        for (int j = 0; j < 8; ++j) {
            int idx = tid + j * 256;
            int row = idx >> 4, slot = idx & 15;
            u32x4 kd = *(const u32x4*)(Kb + (size_t)(kbase + row) * DIM + slot * 8);
            *(u32x4*)((char*)Kt + swzo(row, slot * 16)) = kd;
            u32x4 vd = *(const u32x4*)(Vb + (size_t)row * S_LEN + kbase + slot * 8);
            *(u32x4*)((char*)Vl + swzo(row, slot * 16)) = vd;
        }
        __syncthreads();

        #pragma unroll
        for (int kb = 0; kb < 4; ++kb) {
            int ksub = kb * 32;
            int kmin = kbase + ksub;
            if (kmin > qw + 63) break;          // fully masked for this wave
            bool do0 = (kmin <= qw + 31);       // qblock0 still active?

            // S^T = K . Q^T  (lane holds P column q = qw + qb*32 + lr)
            f32x16 s0, s1;
            #pragma unroll
            for (int r = 0; r < 16; ++r) { s0[r] = 0.f; s1[r] = 0.f; }
            #pragma unroll
            for (int h = 0; h < 2; ++h) {       // d in two halves (VGPR economy)
                bf16x8 af[4];
                #pragma unroll
                for (int s2 = 0; s2 < 4; ++s2)
                    af[s2] = *(const bf16x8*)((const char*)Kt +
                        swzo(ksub + lr, (h * 64 + s2 * 16 + lg * 8) * 2));
                #pragma unroll
                for (int s2 = 0; s2 < 4; ++s2) {
                    if (do0) s0 = MFMA32(af[s2], qf[0][h * 4 + s2], s0);
                    s1 = MFMA32(af[s2], qf[1][h * 4 + s2], s1);
                }
            }

            // causal mask: zero k > q (C layout: col=lane&31=q, row=crow(reg)=k)
            if (kmin + 31 > qw) {
                #pragma unroll
                for (int r = 0; r < 16; ++r) {
                    int kg = kmin + (r & 3) + ((r >> 2) << 3) + (lg << 2);
                    if (kg > qw + lr)      s0[r] = 0.f;
                    if (kg > qw + 32 + lr) s1[r] = 0.f;
                }
            }

            // P -> bf16 A-fragments via cvt_pk + permlane32_swap (no LDS trip)
            unsigned int w0[8], w1[8];
            cvt_swap(s0, w0);
            cvt_swap(s1, w1);
            u32x4 t00 = {w0[0], w0[1], w0[2], w0[3]};
            u32x4 t01 = {w0[4], w0[5], w0[6], w0[7]};
            u32x4 t10 = {w1[0], w1[1], w1[2], w1[3]};
            u32x4 t11 = {w1[4], w1[5], w1[6], w1[7]};
            bf16x8 p00 = __builtin_bit_cast(bf16x8, t00);
            bf16x8 p01 = __builtin_bit_cast(bf16x8, t01);
            bf16x8 p10 = __builtin_bit_cast(bf16x8, t10);
            bf16x8 p11 = __builtin_bit_cast(bf16x8, t11);

            // O += P . V ; V-frags shared across both q-blocks
            #pragma unroll
            for (int db = 0; db < 4; ++db) {
                bf16x8 vb0 = *(const bf16x8*)((const char*)Vl +
                    swzo(db * 32 + lr, (ksub + lg * 8) * 2));
                bf16x8 vb1 = *(const bf16x8*)((const char*)Vl +
                    swzo(db * 32 + lr, (ksub + 16 + lg * 8) * 2));
                if (do0) {
                    acc[0][db] = MFMA32(p00, vb0, acc[0][db]);
                    acc[0][db] = MFMA32(p01, vb1, acc[0][db]);
                }
                acc[1][db] = MFMA32(p10, vb0, acc[1][db]);
                acc[1][db] = MFMA32(p11, vb1, acc[1][db]);
            }
        }
        __syncthreads();
    }

    // epilogue: C layout col=lane&31=d, row=(r&3)+8*(r>>2)+4*lg = q offset
    float* Ob = Out + (size_t)b * S_LEN * DIM;
    #pragma unroll
    for (int qb = 0; qb < 2; ++qb)
        #pragma unroll
        for (int db = 0; db < 4; ++db)
            #pragma unroll
            for (int r = 0; r < 16; ++r) {
                int q = qw + qb * 32 + (r & 3) + ((r >> 2) << 3) + (lg << 2);
                int d = db * 32 + lr;
                float v = acc[qb][db][r];
                float* p = Ob + (size_t)q * DIM + d;
                if (single) *p = v; else atomicAdd(p, v);
            }
}

extern "C" void kernel_launch(void* const* d_in, const int* in_sizes, int n_in,
                              void* d_out, int out_size, void* d_ws, size_t ws_size,
                              hipStream_t stream) {
    const float* Q = (const float*)d_in[0];
    const float* K = (const float*)d_in[1];
    const float* V = (const float*)d_in[2];
    float* Out = (float*)d_out;

    size_t planeBytes = (size_t)NB * S_LEN * DIM * sizeof(bf16_t); // 4 MB
    if (ws_size < 3 * planeBytes) return;   // need 12 MB scratch
    char* wsb = (char*)d_ws;
    bf16_t* Qr = (bf16_t*)wsb;
    bf16_t* Kr = (bf16_t*)(wsb + planeBytes);
    bf16_t* Vt = (bf16_t*)(wsb + 2 * planeBytes);

    hipMemsetAsync(d_out, 0, (size_t)NB * S_LEN * DIM * sizeof(float), stream);

    rope_pack_kernel<<<NB * S_LEN / 4, 256, 0, stream>>>(Q, K, Qr, Kr);
    vt_pack_kernel<<<dim3(S_LEN / 64, NB), 256, 0, stream>>>(V, Vt);

    int chunks = 0;
    for (int i = 0; i < NQT; ++i) chunks += (2 * (i + 1) + CH - 1) / CH;  // 96
    attn_main_kernel<<<NB * chunks, 256, 0, stream>>>(Qr, Kr, Vt, Out);
}